// Round 18
// baseline (202.738 us; speedup 1.0000x reference)
//
#include <hip/hip_runtime.h>

#define BB 4
#define CC 128
#define HH 180
#define WWW 180
#define HWHW (HH*WWW)       // 32400
#define CCAMD 256
#define NHEADS 4
#define HDD 128
#define NT 20000
#define MTOT 80000          // B*N, = 625 * 128 exactly
#define GAMMA_C 0.08f
#define EPS_C 1e-6f
#define SCALE_C 0.17677669529663687f  // 1/sqrt(32)

typedef short bf16x8 __attribute__((ext_vector_type(8)));
typedef float f32x4 __attribute__((ext_vector_type(4)));

typedef __attribute__((address_space(1))) const unsigned int GU;
typedef __attribute__((address_space(3))) unsigned int LU;

static __device__ __forceinline__ void gll16(const void* g, void* l) {
  __builtin_amdgcn_global_load_lds((GU*)g, (LU*)l, 16, 0, 0);
}

#define WAIT_VMCNT0() asm volatile("s_waitcnt vmcnt(0)" ::: "memory")
#define WAIT_VMCNT2() asm volatile("s_waitcnt vmcnt(2)" ::: "memory")
#define WAIT_VMCNT3() asm volatile("s_waitcnt vmcnt(3)" ::: "memory")
#define WAIT_LGKM0()  asm volatile("s_waitcnt lgkmcnt(0)" ::: "memory")

static __device__ __forceinline__ unsigned short f2bf(float x) {
  unsigned int b = __float_as_uint(x);
  unsigned int r = (b + 0x7fffu + ((b >> 16) & 1u)) >> 16;
  return (unsigned short)r;
}
static __device__ __forceinline__ float b2f(unsigned short u) {
  return __uint_as_float(((unsigned int)u) << 16);
}

static __device__ __forceinline__ float warpMax(float v) {
#pragma unroll
  for (int o = 32; o >= 1; o >>= 1) v = fmaxf(v, __shfl_xor(v, o));
  return v;
}
static __device__ __forceinline__ float warpSum(float v) {
#pragma unroll
  for (int o = 32; o >= 1; o >>= 1) v += __shfl_xor(v, o);
  return v;
}
static __device__ __forceinline__ int warpSumI(int v) {
#pragma unroll
  for (int o = 32; o >= 1; o >>= 1) v += __shfl_xor(v, o);
  return v;
}

// ---------------------------------------------------------------------------
// k_prep_pix: blocks 0..95: weight f32->bf16; blocks 96..408: pixel indices +
// int histogram cnt_pix[b][pix]++.
// ---------------------------------------------------------------------------
__global__ __launch_bounds__(256) void k_prep_pix(
    const float* __restrict__ kw, const float* __restrict__ vw,
    const float* __restrict__ qw, const float* __restrict__ ow,
    unsigned short* __restrict__ kvw, unsigned short* __restrict__ qwb,
    unsigned short* __restrict__ owb, const int* __restrict__ cidx,
    int* __restrict__ pix_ws, int* __restrict__ cnt_pix)
{
  if (blockIdx.x < 96) {
    const int t = blockIdx.x * 256 + threadIdx.x;  // one float4 per thread
    float4 f;
    unsigned short* dst;
    if (t < 16384) {           // kv: 65536 elems
      f = (t < 8192) ? ((const float4*)kw)[t] : ((const float4*)vw)[t - 8192];
      dst = kvw + (size_t)t * 4;
    } else if (t < 20480) {    // q: 16384 elems
      const int i = t - 16384;
      f = ((const float4*)qw)[i];
      dst = qwb + (size_t)i * 4;
    } else {                   // out: 16384 elems
      const int i = t - 20480;
      f = ((const float4*)ow)[i];
      dst = owb + (size_t)i * 4;
    }
    ushort4 u;
    u.x = f2bf(f.x); u.y = f2bf(f.y); u.z = f2bf(f.z); u.w = f2bf(f.w);
    *(ushort4*)dst = u;
  } else {
    const int t = (blockIdx.x - 96) * 256 + threadIdx.x;
    if (t >= MTOT) return;
    const int2 ij = *(const int2*)(cidx + (size_t)t * 2);
    int ii = ij.x; ii = ii < 0 ? 0 : (ii > HH - 1 ? HH - 1 : ii);
    int jj = ij.y; jj = jj < 0 ? 0 : (jj > WWW - 1 ? WWW - 1 : jj);
    const int pix = ii * WWW + jj;
    pix_ws[t] = pix;
    atomicAdd(cnt_pix + (size_t)(t / NT) * HWHW + pix, 1);
  }
}

// ---------------------------------------------------------------------------
// k_tr2b: lidar_t[b][p][:] = lidar[b][:][p], one thread per pixel row
// (256B contiguous write).
// ---------------------------------------------------------------------------
__global__ __launch_bounds__(512) void k_tr2b(
    const float* __restrict__ lidar, unsigned short* __restrict__ lidar_t)
{
  const int idx = blockIdx.x * 512 + threadIdx.x;
  if (idx >= BB * HWHW) return;
  const int b = idx / HWHW, p = idx - b * HWHW;
  const float* src = lidar + (size_t)b * CC * HWHW + p;
  unsigned short* dst = lidar_t + (size_t)idx * 128;
#pragma unroll
  for (int c8 = 0; c8 < 16; ++c8) {
    bf16x8 v;
#pragma unroll
    for (int e = 0; e < 8; ++e)
      v[e] = (short)f2bf(src[(size_t)(c8 * 8 + e) * HWHW]);
    ((bf16x8*)dst)[c8] = v;
  }
}

// ---------------------------------------------------------------------------
// k_scanA: bsum[b][blk] = sum of cnt_pix[b][blk*512 .. +512); also
// accumulates per-batch hit-pixel count into cntB[b].
// ---------------------------------------------------------------------------
__global__ __launch_bounds__(512) void k_scanA(
    const int* __restrict__ cnt, int* __restrict__ bsum,
    float* __restrict__ cntB)
{
  const int b = blockIdx.y, blk = blockIdx.x;
  const int idx = blk * 512 + threadIdx.x;
  int v = (idx < HWHW) ? cnt[(size_t)b * HWHW + idx] : 0;
  int h = (v > 0) ? 1 : 0;
  v = warpSumI(v);
  h = warpSumI(h);
  __shared__ int ws[8], hs[8];
  const int wave = threadIdx.x >> 6, lane = threadIdx.x & 63;
  if (lane == 0) { ws[wave] = v; hs[wave] = h; }
  __syncthreads();
  if (threadIdx.x == 0) {
    int sv = 0, sh = 0;
#pragma unroll
    for (int w = 0; w < 8; ++w) { sv += ws[w]; sh += hs[w]; }
    bsum[b * 64 + blk] = sv;
    atomicAdd(cntB + b, (float)sh);
  }
}

// ---------------------------------------------------------------------------
// k_scanB: boff[b][*] = exclusive scan of bsum[b][*] (64 entries, 1 wave)
// ---------------------------------------------------------------------------
__global__ __launch_bounds__(64) void k_scanB(
    const int* __restrict__ bsum, int* __restrict__ boff)
{
  const int b = blockIdx.x, t = threadIdx.x;
  const int v = bsum[b * 64 + t];
  int inc = v;
#pragma unroll
  for (int off = 1; off < 64; off <<= 1) {
    int u = __shfl_up(inc, off, 64);
    if (t >= off) inc += u;
  }
  boff[b * 64 + t] = inc - v;
}

// ---------------------------------------------------------------------------
// k_kv2: kv projection [80000,256] x [256,256]^T -> kv_bf, BARRIER-FREE
// K-loop. B (128 weight rows x 256) preloaded ONCE into LDS (64KB,
// XOR-swizzled: physical chunk = logical ^ (row&7) -> 2-way banks).
// A rows are wave-private (wave owns 32 rows): per-lane contiguous f32
// loads straight to registers; fully unrolled loop, no s_barrier and no
// manual s_waitcnt -> compiler hoists A loads, waves free-run (TLP hides
// HBM latency). 8 waves = 4 row-groups x 2 col-groups; acc[2][4].
// ---------------------------------------------------------------------------
__global__ __launch_bounds__(512) void k_kv2(
    const float* __restrict__ tokens, const unsigned short* __restrict__ kvw,
    unsigned short* __restrict__ kv_bf)
{
  __shared__ unsigned short Bl[128 * 256];   // 64KB
  const int tid = threadIdx.x;
  const int lane = tid & 63, wave = tid >> 6;
  const int wm = wave >> 1, wn = wave & 1;   // 4 x 2
  const int l16 = lane & 15, kg = lane >> 4;
  const int mblk = blockIdx.x, nblk = blockIdx.y;

  // ---- B preload: physical slot s holds logical chunk (s ^ (row&7));
  // reads use the same XOR (involution). 8 slots (16B) per thread.
#pragma unroll
  for (int i = 0; i < 8; ++i) {
    const int s = i * 512 + tid;             // slot id 0..4095
    const int row = s >> 5, sc = s & 31;     // 32 chunks per row
    const unsigned short* src =
        kvw + (size_t)(nblk * 128 + row) * CCAMD + ((sc ^ (row & 7)) << 3);
    gll16(src, &Bl[(size_t)(i * 512 + wave * 64) * 8]);
  }
  WAIT_VMCNT0();
  __syncthreads();                            // the only barrier

  // ---- wave-private A rows ----
  const float* a0 =
      tokens + (size_t)(mblk * 128 + wm * 32 + l16) * CCAMD + kg * 8;
  const float* a1 = a0 + (size_t)16 * CCAMD;

  f32x4 acc[2][4];
#pragma unroll
  for (int i = 0; i < 2; ++i)
#pragma unroll
    for (int j = 0; j < 4; ++j) acc[i][j] = (f32x4)0.0f;

#pragma unroll
  for (int kt = 0; kt < 8; ++kt) {
    bf16x8 a[2];
    {
      const float4 f0 = *(const float4*)(a0 + kt * 32);
      const float4 f1 = *(const float4*)(a0 + kt * 32 + 4);
      bf16x8 v;
      v[0] = (short)f2bf(f0.x); v[1] = (short)f2bf(f0.y);
      v[2] = (short)f2bf(f0.z); v[3] = (short)f2bf(f0.w);
      v[4] = (short)f2bf(f1.x); v[5] = (short)f2bf(f1.y);
      v[6] = (short)f2bf(f1.z); v[7] = (short)f2bf(f1.w);
      a[0] = v;
    }
    {
      const float4 f0 = *(const float4*)(a1 + kt * 32);
      const float4 f1 = *(const float4*)(a1 + kt * 32 + 4);
      bf16x8 v;
      v[0] = (short)f2bf(f0.x); v[1] = (short)f2bf(f0.y);
      v[2] = (short)f2bf(f0.z); v[3] = (short)f2bf(f0.w);
      v[4] = (short)f2bf(f1.x); v[5] = (short)f2bf(f1.y);
      v[6] = (short)f2bf(f1.z); v[7] = (short)f2bf(f1.w);
      a[1] = v;
    }
    bf16x8 b[4];
#pragma unroll
    for (int nf = 0; nf < 4; ++nf) {
      const int row = wn * 64 + nf * 16 + l16;
      const int ch = (kt * 4 + kg) ^ (row & 7);
      b[nf] = *(const bf16x8*)&Bl[row * 256 + ch * 8];
    }
#pragma unroll
    for (int mf = 0; mf < 2; ++mf)
#pragma unroll
      for (int nf = 0; nf < 4; ++nf)
        acc[mf][nf] =
            __builtin_amdgcn_mfma_f32_16x16x32_bf16(a[mf], b[nf], acc[mf][nf], 0, 0, 0);
  }

  // ---- epilogue: bf16 rows into kv_bf[row][256] at col nblk*128 ----
#pragma unroll
  for (int mf = 0; mf < 2; ++mf) {
#pragma unroll
    for (int j = 0; j < 4; ++j) {
      const int row = mblk * 128 + wm * 32 + mf * 16 + kg * 4 + j;
      unsigned short* dr = kv_bf + (size_t)row * 256 + nblk * 128 + wn * 64 + l16;
#pragma unroll
      for (int nf = 0; nf < 4; ++nf)
        dr[nf * 16] = f2bf(acc[mf][nf][j]);
    }
  }
}

// ---------------------------------------------------------------------------
// pipe_body: pipelined GEMM C[M,128cols@nblk] = A[M,KW] x W^T (MFMA 16x16x32).
// BM=128, BN=128, BK=32, 512 thr (8 waves 2x4, acc[4][2]).
// 3 LDS buffers, DIST=2 prefetch, counted vmcnt, raw s_barrier (round-13).
// AMODE 0: A f32 rows. AMODE 2: A bf16 rows gathered via pixw.
// AMODE 4: A = V-half of kv_bf in SORTED order x softmax*gate coef.
// EPI 0: bf16 rows. EPI 2: per-head logits vs kvb. EPI 3: linear bf16 +
// column sums -> meanr.
// ---------------------------------------------------------------------------
template<int KSTEPS, int KW, int AMODE, int EPI, int NOUT>
static __device__ void pipe_body(
    int mblk, int nblk, unsigned short* lds,
    const float* __restrict__ Af32, const unsigned short* __restrict__ Abf,
    const unsigned short* __restrict__ Bw, const float* __restrict__ bias,
    unsigned short* __restrict__ Dbf, const int* __restrict__ pixw,
    float* __restrict__ aux, const unsigned short* __restrict__ kvb,
    float* __restrict__ meanr, const float* __restrict__ smMp,
    const float* __restrict__ smSinvp, const float* __restrict__ gatep,
    const float* __restrict__ logp, const int* __restrict__ sortn)
{
  const int tid = threadIdx.x;
  const int lane = tid & 63, wave = tid >> 6;   // 8 waves
  const int wm = wave >> 2, wn = wave & 3;      // 2 x 4
  const int l16 = lane & 15, kg = lane >> 4;
  const int sr_rd = (l16 >> 1) & 3;             // read-side swizzle key

  // staging geometry: each thread owns one 16B chunk of one row
  const int row_s = wave * 16 + (lane >> 2);    // 0..127
  const int chunk_s = lane & 3;
  const int swz_s = chunk_s ^ ((lane >> 3) & 3);  // == chunk ^ ((row_s>>1)&3)
  const int a_dst = row_s * 32 + swz_s * 8;       // ushort idx (swizzled dest)

  const unsigned short* bsrc = Bw + (size_t)(nblk * 128 + row_s) * KW + swz_s * 8;

  const float* asrc_f32 = nullptr;
  const unsigned short* asrc_bf = nullptr;
  float coef4[4] = {0.f, 0.f, 0.f, 0.f};
  if constexpr (AMODE == 0) {
    asrc_f32 = Af32 + (size_t)(mblk * 128 + row_s) * KW + chunk_s * 8;
  } else if constexpr (AMODE == 2) {
    const int r = mblk * 128 + row_s;
    const int bb = r / NT;
    asrc_bf = Abf + ((size_t)bb * HWHW + pixw[r]) * 128 + swz_s * 8;
  } else {  // AMODE 4: sorted V
    const int r = mblk * 128 + row_s;
    const int bb = r / NT, pos = r - bb * NT;
    const int n = sortn[(size_t)bb * NT + pos];
    asrc_bf = Abf + ((size_t)bb * NT + n) * 256 + 128 + chunk_s * 8;
    const float ga = gatep[(size_t)bb * NT + n];
#pragma unroll
    for (int h = 0; h < 4; ++h) {
      const int bh = bb * NHEADS + h;
      coef4[h] = __expf(logp[(size_t)bh * NT + n] - smMp[bh]) * smSinvp[bh] * ga;
    }
  }

  f32x4 acc[4][2];
#pragma unroll
  for (int i = 0; i < 4; ++i)
#pragma unroll
    for (int j = 0; j < 2; ++j) acc[i][j] = (f32x4)0.0f;

  float4 afx[2], afy[2];   // AMODE 0
  bf16x8 av[2];            // AMODE 4

  auto issueA = [&](int kt, int s, int buf) {
    if constexpr (AMODE == 0) {
      afx[s] = *(const float4*)(asrc_f32 + kt * 32);
      afy[s] = *(const float4*)(asrc_f32 + kt * 32 + 4);
    } else if constexpr (AMODE == 2) {
      gll16(asrc_bf + kt * 32, &lds[buf * 8192 + wave * 512]);
    } else {
      av[s] = *(const bf16x8*)(asrc_bf + kt * 32);
    }
  };
  auto issueB = [&](int kt, int buf) {
    gll16(bsrc + kt * 32, &lds[buf * 8192 + 4096 + wave * 512]);
  };
  auto writeA = [&](int kt, int s, int buf) {
    bf16x8 v;
    if constexpr (AMODE == 0) {
      v[0] = (short)f2bf(afx[s].x); v[1] = (short)f2bf(afx[s].y);
      v[2] = (short)f2bf(afx[s].z); v[3] = (short)f2bf(afx[s].w);
      v[4] = (short)f2bf(afy[s].x); v[5] = (short)f2bf(afy[s].y);
      v[6] = (short)f2bf(afy[s].z); v[7] = (short)f2bf(afy[s].w);
    } else {
      const float c = coef4[kt];
#pragma unroll
      for (int e = 0; e < 8; ++e)
        v[e] = (short)f2bf(b2f((unsigned short)av[s][e]) * c);
    }
    *(bf16x8*)&lds[buf * 8192 + a_dst] = v;
  };
  auto compute = [&](int buf) {
    const int base = buf * 8192;
    bf16x8 a[4], b[2];
#pragma unroll
    for (int mf = 0; mf < 4; ++mf) {
      const int row = wm * 64 + mf * 16 + l16;
      a[mf] = *(const bf16x8*)&lds[base + row * 32 + ((kg ^ sr_rd) << 3)];
    }
#pragma unroll
    for (int nf = 0; nf < 2; ++nf) {
      const int row = wn * 32 + nf * 16 + l16;
      b[nf] = *(const bf16x8*)&lds[base + 4096 + row * 32 + ((kg ^ sr_rd) << 3)];
    }
#pragma unroll
    for (int mf = 0; mf < 4; ++mf)
#pragma unroll
      for (int nf = 0; nf < 2; ++nf)
        acc[mf][nf] =
            __builtin_amdgcn_mfma_f32_16x16x32_bf16(a[mf], b[nf], acc[mf][nf], 0, 0, 0);
  };

  // ---- prologue: 2 tiles in flight ----
  issueA(0, 0, 0); issueB(0, 0);
  issueA(1, 1, 1); issueB(1, 1);
  if constexpr (AMODE != 2) writeA(0, 0, 0);

  // ---- counted-vmcnt pipelined K-loop (T3+T4) ----
#pragma unroll
  for (int t = 0; t < KSTEPS; ++t) {
    if (t < KSTEPS - 1) {
      if constexpr (AMODE == 0) WAIT_VMCNT3(); else WAIT_VMCNT2();
    } else {
      WAIT_VMCNT0();
    }
    WAIT_LGKM0();                       // own writeA(t) committed
    __builtin_amdgcn_s_barrier();       // all waves: buf[t%3] valid
    __builtin_amdgcn_sched_barrier(0);
    if (t + 2 < KSTEPS) {               // prefetch into buf[(t-1)%3] (free now)
      issueA(t + 2, t & 1, (t + 2) % 3);
      issueB(t + 2, (t + 2) % 3);
    }
    compute(t % 3);
    if constexpr (AMODE != 2) {
      if (t + 1 < KSTEPS) writeA(t + 1, (t + 1) & 1, (t + 1) % 3);
    }
  }
  __syncthreads();

  float* scratch = (float*)lds;

  // ---- epilogue ----
  if constexpr (EPI == 0) {
#pragma unroll
    for (int mf = 0; mf < 4; ++mf) {
#pragma unroll
      for (int j = 0; j < 4; ++j) {
        const int row = mblk * 128 + wm * 64 + mf * 16 + kg * 4 + j;
        unsigned short* dr = Dbf + (size_t)row * NOUT + nblk * 128 + wn * 32 + l16;
#pragma unroll
        for (int nf = 0; nf < 2; ++nf)
          dr[nf * 16] = f2bf(acc[mf][nf][j]);
      }
    }
  } else if constexpr (EPI == 2) {
    // logits. Wave's 32-col span = head wn. Reduce over l16 group.
    float bv[2];
#pragma unroll
    for (int nf = 0; nf < 2; ++nf)
      bv[nf] = bias[wn * 32 + nf * 16 + l16];
#pragma unroll
    for (int mf = 0; mf < 4; ++mf) {
#pragma unroll
      for (int j = 0; j < 4; ++j) {
        const int rl = wm * 64 + mf * 16 + kg * 4 + j;
        const int row = mblk * 128 + rl;
        const unsigned short* kr = kvb + (size_t)row * 256 + wn * 32 + l16;
        float s = (acc[mf][0][j] + bv[0]) * b2f(kr[0]) +
                  (acc[mf][1][j] + bv[1]) * b2f(kr[16]);
        s += __shfl_xor(s, 8, 16); s += __shfl_xor(s, 4, 16);
        s += __shfl_xor(s, 2, 16); s += __shfl_xor(s, 1, 16);
        if (l16 == 0) scratch[rl * 4 + wn] = s;
      }
    }
    __syncthreads();
    if (tid < 128) {
      const int row = mblk * 128 + tid;
      const int bb = row / NT, n = row - bb * NT;
#pragma unroll
      for (int h = 0; h < 4; ++h)
        aux[((size_t)bb * NHEADS + h) * NT + n] = scratch[tid * 4 + h] * SCALE_C;
    }
  } else {
    // EPI 3: linear bf16 store + block column sums -> meanr
    if (tid < 256) scratch[tid] = 0.0f;
    __syncthreads();
    const int b0 = (mblk * 128) / NT;
#pragma unroll
    for (int mf = 0; mf < 4; ++mf) {
      const int baser = mblk * 128 + wm * 64 + mf * 16 + kg * 4;
      const int bb = baser / NT;          // uniform over j (NT % 4 == 0)
      const int bsel = (bb != b0) ? 1 : 0;
      float s[2] = {0.0f, 0.0f};
#pragma unroll
      for (int j = 0; j < 4; ++j) {
        const int row = baser + j;
        unsigned short* dr = Dbf + (size_t)row * 128 + wn * 32 + l16;
#pragma unroll
        for (int nf = 0; nf < 2; ++nf) {
          dr[nf * 16] = f2bf(acc[mf][nf][j]);
          s[nf] += acc[mf][nf][j];
        }
      }
#pragma unroll
      for (int nf = 0; nf < 2; ++nf)
        atomicAdd(&scratch[bsel * 128 + wn * 32 + nf * 16 + l16], s[nf]);
    }
    __syncthreads();
    const int b1 = (mblk * 128 + 127) / NT;
    if (tid < 128) atomicAdd(meanr + (size_t)b0 * 128 + tid, scratch[tid]);
    else if (tid < 256 && b1 != b0)
      atomicAdd(meanr + (size_t)b1 * 128 + (tid - 128), scratch[tid]);
  }
}

// ---------------------------------------------------------------------------
// k_m2: blocks [0,256): scanC (start = boff + in-block exclusive scan);
//       blocks [256,881): q GEMM (gathered lidar_t rows) -> per-head logits.
// ---------------------------------------------------------------------------
__global__ __launch_bounds__(512) void k_m2(
    const int* __restrict__ cnt_pix, const int* __restrict__ boff,
    int* __restrict__ start, const unsigned short* __restrict__ lidar_t,
    const unsigned short* __restrict__ qwb, const float* __restrict__ qb,
    const int* __restrict__ pixw, float* __restrict__ logits,
    const unsigned short* __restrict__ kv_bf)
{
  __shared__ unsigned short lds[24576];
  const int bid = blockIdx.x;
  if (bid < 256) {
    __shared__ int ws[8];
    const int b = bid >> 6, blk = bid & 63;
    const int idx = blk * 512 + threadIdx.x;
    const int wave = threadIdx.x >> 6, lane = threadIdx.x & 63;
    int v = (idx < HWHW) ? cnt_pix[(size_t)b * HWHW + idx] : 0;
    int inc = v;
#pragma unroll
    for (int off = 1; off < 64; off <<= 1) {
      int u = __shfl_up(inc, off, 64);
      if (lane >= off) inc += u;
    }
    if (lane == 63) ws[wave] = inc;
    __syncthreads();
    int wo = 0;
#pragma unroll
    for (int w = 0; w < 8; ++w)
      if (w < wave) wo += ws[w];
    if (idx < HWHW)
      start[(size_t)b * HWHW + idx] = boff[b * 64 + blk] + wo + inc - v;
  } else {
    pipe_body<4, 128, 2, 2, 128>(bid - 256, 0, lds, nullptr, lidar_t, qwb,
                                 qb, nullptr, pixw, logits, kv_bf, nullptr,
                                 nullptr, nullptr, nullptr, nullptr, nullptr);
  }
}

// ---------------------------------------------------------------------------
// k_m3: blocks [0,128): smpart; blocks [128,441): reorder.
// ---------------------------------------------------------------------------
__global__ __launch_bounds__(256) void k_m3(
    const float* __restrict__ logits, float* __restrict__ pm,
    float* __restrict__ ps, const int* __restrict__ pix_ws,
    const int* __restrict__ start, int* __restrict__ fill,
    int* __restrict__ sortn)
{
  const int bid = blockIdx.x;
  if (bid < 128) {
    const int ch = bid & 7, bh = bid >> 3;
    const float* L = logits + (size_t)bh * NT + ch * 2500;
    const int tid = threadIdx.x;
    __shared__ float sred[4];

    float m = -INFINITY;
    for (int i = tid; i < 2500; i += 256) m = fmaxf(m, L[i]);
    m = warpMax(m);
    if ((tid & 63) == 0) sred[tid >> 6] = m;
    __syncthreads();
    m = fmaxf(fmaxf(sred[0], sred[1]), fmaxf(sred[2], sred[3]));

    float s = 0.0f;
    for (int i = tid; i < 2500; i += 256) s += __expf(L[i] - m);
    s = warpSum(s);
    __syncthreads();
    if ((tid & 63) == 0) sred[tid >> 6] = s;
    __syncthreads();
    if (tid == 0) {
      pm[bh * 8 + ch] = m;
      ps[bh * 8 + ch] = sred[0] + sred[1] + sred[2] + sred[3];
    }
  } else {
    const int t = (bid - 128) * 256 + threadIdx.x;
    if (t >= MTOT) return;
    const int b = t / NT, n = t - b * NT;
    const int pix = pix_ws[t];
    const int pos = atomicAdd(fill + (size_t)b * HWHW + pix, 1);
    sortn[(size_t)b * NT + start[(size_t)b * HWHW + pix] + pos] = n;
  }
}

// ---------------------------------------------------------------------------
// k_smfix: combine softmax partials -> smM, smSinv.
// ---------------------------------------------------------------------------
__global__ __launch_bounds__(64) void k_smfix(
    const float* __restrict__ pm, const float* __restrict__ ps,
    float* __restrict__ smM, float* __restrict__ smSinv)
{
  const int t = threadIdx.x;
  if (t >= BB * NHEADS) return;
  float M = -INFINITY;
#pragma unroll
  for (int c = 0; c < 8; ++c) M = fmaxf(M, pm[t * 8 + c]);
  float S = 0.0f;
#pragma unroll
  for (int c = 0; c < 8; ++c) S += ps[t * 8 + c] * __expf(pm[t * 8 + c] - M);
  smM[t] = M;
  smSinv[t] = 1.0f / S;
}

// ---------------------------------------------------------------------------
// k_out: out projection over SORTED tokens -> out_tok + column sums.
// ---------------------------------------------------------------------------
__global__ __launch_bounds__(512) void k_out(
    const unsigned short* __restrict__ kv_bf, const unsigned short* __restrict__ owb,
    unsigned short* __restrict__ out_tok, float* __restrict__ meanr,
    const float* __restrict__ smM, const float* __restrict__ smSinv,
    const float* __restrict__ gate, const float* __restrict__ logits,
    const int* __restrict__ sortn)
{
  __shared__ unsigned short lds[24576];
  pipe_body<4, 128, 4, 3, 128>(blockIdx.x, 0, lds, nullptr, kv_bf, owb,
                               nullptr, out_tok, nullptr, nullptr, nullptr,
                               meanr, smM, smSinv, gate, logits, sortn);
}

// ---------------------------------------------------------------------------
// k_final2: out[b][c][hw] = lidar + (delta - mean*mask)*alpha*gamma where
// delta[p][c] = sum over p's tokens of out_tok rows (sorted -> contiguous).
// ---------------------------------------------------------------------------
__global__ __launch_bounds__(512) void k_final2(
    const float* __restrict__ lidar, const float* __restrict__ alpha,
    const int* __restrict__ cnt_pix, const int* __restrict__ start,
    const unsigned short* __restrict__ out_tok,
    const float* __restrict__ mean_raw, const float* __restrict__ cntB,
    float* __restrict__ out)
{
  __shared__ float tile[80 * 136];
  const int b = blockIdx.y;
  const int p0 = blockIdx.x * 80;
  const int t = threadIdx.x;

  // phase 1: per-pixel token reduction (16 pixel-groups x 32 lanes)
  const int g = t >> 5, l32 = t & 31;
#pragma unroll
  for (int i = 0; i < 5; ++i) {
    const int pl = i * 16 + g;            // 0..79
    const int p = p0 + pl;
    const int st = start[(size_t)b * HWHW + p];
    const int cn = cnt_pix[(size_t)b * HWHW + p];
    float4 a = make_float4(0.0f, 0.0f, 0.0f, 0.0f);
    const unsigned short* rp = out_tok + ((size_t)b * NT + st) * 128 + l32 * 4;
    for (int k = 0; k < cn; ++k) {
      const ushort4 u = *(const ushort4*)(rp + (size_t)k * 128);
      a.x += b2f(u.x); a.y += b2f(u.y); a.z += b2f(u.z); a.w += b2f(u.w);
    }
    *(float4*)&tile[pl * 136 + ((l32 ^ (pl & 7)) << 2)] = a;
  }
  __syncthreads();

  // phase 2: transpose + final combine
  const int c = t >> 2, sub = t & 3;
  const int cq = c >> 2, cr = c & 3;
  const float mn = mean_raw[b * 128 + c] / (cntB[b] + EPS_C);
  const size_t cbase = ((size_t)b * CC + c) * HWHW + p0;
  const int* cnb = cnt_pix + (size_t)b * HWHW + p0;
#pragma unroll
  for (int j = 0; j < 5; ++j) {
    const int pq = j * 16 + sub * 4;
    float4 d;
    d.x = tile[(pq + 0) * 136 + (((cq ^ ((pq + 0) & 7)) << 2) | cr)];
    d.y = tile[(pq + 1) * 136 + (((cq ^ ((pq + 1) & 7)) << 2) | cr)];
    d.z = tile[(pq + 2) * 136 + (((cq ^ ((pq + 2) & 7)) << 2) | cr)];
    d.w = tile[(pq + 3) * 136 + (((cq ^ ((pq + 3) & 7)) << 2) | cr)];
    const float4 li = *(const float4*)(lidar + cbase + pq);
    const float4 al = *(const float4*)(alpha + p0 + pq);
    const int4 hc = *(const int4*)(cnb + pq);
    float4 o;
    o.x = li.x + (d.x - (hc.x > 0 ? mn : 0.0f)) * al.x * GAMMA_C;
    o.y = li.y + (d.y - (hc.y > 0 ? mn : 0.0f)) * al.y * GAMMA_C;
    o.z = li.z + (d.z - (hc.z > 0 ? mn : 0.0f)) * al.z * GAMMA_C;
    o.w = li.w + (d.w - (hc.w > 0 ? mn : 0.0f)) * al.w * GAMMA_C;
    *(float4*)(out + cbase + pq) = o;
  }
}

// ---------------------------------------------------------------------------
extern "C" void kernel_launch(void* const* d_in, const int* in_sizes, int n_in,
                              void* d_out, int out_size, void* d_ws, size_t ws_size,
                              hipStream_t stream)
{
  const float* lidar  = (const float*)d_in[0];
  const float* tokens = (const float*)d_in[1];
  const float* gate   = (const float*)d_in[2];
  const float* alpha  = (const float*)d_in[3];
  const float* q_w    = (const float*)d_in[4];
  const float* q_b    = (const float*)d_in[5];
  const float* k_w    = (const float*)d_in[6];
  const float* v_w    = (const float*)d_in[7];
  const float* out_w  = (const float*)d_in[8];
  const int*   cidx   = (const int*)d_in[9];
  float* out = (float*)d_out;

  char* W = (char*)d_ws;
  unsigned short* kv_bf   = (unsigned short*)(W + 0);          // 40,960,000
  unsigned short* lidar_t = (unsigned short*)(W + 40960000);   // 33,177,600
  unsigned short* out_tok = (unsigned short*)(W + 74137600);   // 20,480,000
  float* logits  = (float*)(W + 94617600);                     //  1,280,000
  int*   pix_ws  = (int*)(W + 95897600);                       //    320,000
  int*   sortn   = (int*)(W + 96217600);                       //    320,000
  int*   cnt_pix = (int*)(W + 96537600);                       //    518,400
  int*   start   = (int*)(W + 97056000);                       //    518,400
  int*   fill    = (int*)(W + 97574400);                       //    518,400
  float* mean_raw = (float*)(W + 98092800);                    //      2,048
  float* cntB     = (float*)(W + 98094848);                    //         64
  unsigned short* kvw_bf = (unsigned short*)(W + 98094912);    //    131,072
  unsigned short* qw_bf  = (unsigned short*)(W + 98225984);    //     32,768
  unsigned short* ow_bf  = (unsigned short*)(W + 98258752);    //     32,768
  float* pm     = (float*)(W + 98291520);                      //        512
  float* ps     = (float*)(W + 98292032);                      //        512
  float* smM    = (float*)(W + 98292544);                      //         64
  float* smSinv = (float*)(W + 98292608);                      //         64
  int*   bsum   = (int*)(W + 98292672);                        //      1,024
  int*   boff   = (int*)(W + 98293696);                        //      1,024

  hipMemsetAsync(cnt_pix, 0, (size_t)BB * HWHW * sizeof(int), stream);
  hipMemsetAsync(fill, 0, (size_t)BB * HWHW * sizeof(int), stream);
  hipMemsetAsync(mean_raw, 0, 2048 + 64, stream);

  k_prep_pix<<<dim3(409), 256, 0, stream>>>(k_w, v_w, q_w, out_w, kvw_bf,
                                            qw_bf, ow_bf, cidx, pix_ws, cnt_pix);
  k_tr2b<<<dim3(254), 512, 0, stream>>>(lidar, lidar_t);
  k_scanA<<<dim3(64, BB), 512, 0, stream>>>(cnt_pix, bsum, cntB);
  k_scanB<<<dim3(BB), 64, 0, stream>>>(bsum, boff);
  // kv projection (barrier-free, B-in-LDS-once): -> kv_bf[row][256]
  k_kv2<<<dim3(625, 2), 512, 0, stream>>>(tokens, kvw_bf, kv_bf);
  // M2: scanC + q GEMM/logits
  k_m2<<<dim3(881), 512, 0, stream>>>(cnt_pix, boff, start, lidar_t, qw_bf,
                                      q_b, pix_ws, logits, kv_bf);
  // M3: smpart + reorder
  k_m3<<<dim3(441), 256, 0, stream>>>(logits, pm, ps, pix_ws, start, fill, sortn);
  k_smfix<<<dim3(1), 64, 0, stream>>>(pm, ps, smM, smSinv);
  // out projection over SORTED tokens -> out_tok (linear bf16) + mean sums
  k_out<<<dim3(625), 512, 0, stream>>>(kv_bf, ow_bf, out_tok, mean_raw,
                                       smM, smSinv, gate, logits, sortn);
  k_final2<<<dim3(405, BB), 512, 0, stream>>>(lidar, alpha, cnt_pix, start,
                                              out_tok, mean_raw, cntB, out);
}

// Round 19
// 184.688 us; speedup vs baseline: 1.0977x; 1.0977x over previous
//
#include <hip/hip_runtime.h>

#define BB 4
#define CC 128
#define HH 180
#define WWW 180
#define HWHW (HH*WWW)       // 32400
#define CCAMD 256
#define NHEADS 4
#define HDD 128
#define NT 20000
#define MTOT 80000          // B*N, = 625 * 128 exactly
#define GAMMA_C 0.08f
#define EPS_C 1e-6f
#define SCALE_C 0.17677669529663687f  // 1/sqrt(32)

typedef short bf16x8 __attribute__((ext_vector_type(8)));
typedef float f32x4 __attribute__((ext_vector_type(4)));

typedef __attribute__((address_space(1))) const unsigned int GU;
typedef __attribute__((address_space(3))) unsigned int LU;

static __device__ __forceinline__ void gll16(const void* g, void* l) {
  __builtin_amdgcn_global_load_lds((GU*)g, (LU*)l, 16, 0, 0);
}

#define WAIT_VMCNT0() asm volatile("s_waitcnt vmcnt(0)" ::: "memory")
#define WAIT_VMCNT2() asm volatile("s_waitcnt vmcnt(2)" ::: "memory")
#define WAIT_VMCNT3() asm volatile("s_waitcnt vmcnt(3)" ::: "memory")
#define WAIT_LGKM0()  asm volatile("s_waitcnt lgkmcnt(0)" ::: "memory")

static __device__ __forceinline__ unsigned short f2bf(float x) {
  unsigned int b = __float_as_uint(x);
  unsigned int r = (b + 0x7fffu + ((b >> 16) & 1u)) >> 16;
  return (unsigned short)r;
}
static __device__ __forceinline__ float b2f(unsigned short u) {
  return __uint_as_float(((unsigned int)u) << 16);
}

static __device__ __forceinline__ float warpMax(float v) {
#pragma unroll
  for (int o = 32; o >= 1; o >>= 1) v = fmaxf(v, __shfl_xor(v, o));
  return v;
}
static __device__ __forceinline__ float warpSum(float v) {
#pragma unroll
  for (int o = 32; o >= 1; o >>= 1) v += __shfl_xor(v, o);
  return v;
}
static __device__ __forceinline__ int warpSumI(int v) {
#pragma unroll
  for (int o = 32; o >= 1; o >>= 1) v += __shfl_xor(v, o);
  return v;
}

// ---------------------------------------------------------------------------
// k_prep_pix: blocks 0..95: weight f32->bf16; blocks 96..408: pixel indices +
// int histogram cnt_pix[b][pix]++.
// ---------------------------------------------------------------------------
__global__ __launch_bounds__(256) void k_prep_pix(
    const float* __restrict__ kw, const float* __restrict__ vw,
    const float* __restrict__ qw, const float* __restrict__ ow,
    unsigned short* __restrict__ kvw, unsigned short* __restrict__ qwb,
    unsigned short* __restrict__ owb, const int* __restrict__ cidx,
    int* __restrict__ pix_ws, int* __restrict__ cnt_pix)
{
  if (blockIdx.x < 96) {
    const int t = blockIdx.x * 256 + threadIdx.x;  // one float4 per thread
    float4 f;
    unsigned short* dst;
    if (t < 16384) {           // kv: 65536 elems
      f = (t < 8192) ? ((const float4*)kw)[t] : ((const float4*)vw)[t - 8192];
      dst = kvw + (size_t)t * 4;
    } else if (t < 20480) {    // q: 16384 elems
      const int i = t - 16384;
      f = ((const float4*)qw)[i];
      dst = qwb + (size_t)i * 4;
    } else {                   // out: 16384 elems
      const int i = t - 20480;
      f = ((const float4*)ow)[i];
      dst = owb + (size_t)i * 4;
    }
    ushort4 u;
    u.x = f2bf(f.x); u.y = f2bf(f.y); u.z = f2bf(f.z); u.w = f2bf(f.w);
    *(ushort4*)dst = u;
  } else {
    const int t = (blockIdx.x - 96) * 256 + threadIdx.x;
    if (t >= MTOT) return;
    const int2 ij = *(const int2*)(cidx + (size_t)t * 2);
    int ii = ij.x; ii = ii < 0 ? 0 : (ii > HH - 1 ? HH - 1 : ii);
    int jj = ij.y; jj = jj < 0 ? 0 : (jj > WWW - 1 ? WWW - 1 : jj);
    const int pix = ii * WWW + jj;
    pix_ws[t] = pix;
    atomicAdd(cnt_pix + (size_t)(t / NT) * HWHW + pix, 1);
  }
}

// ---------------------------------------------------------------------------
// k_tr2b: lidar_t[b][p][:] = lidar[b][:][p], one thread per pixel row
// (256B contiguous write). Reads coalesced across the wave per channel.
// ---------------------------------------------------------------------------
__global__ __launch_bounds__(512) void k_tr2b(
    const float* __restrict__ lidar, unsigned short* __restrict__ lidar_t)
{
  const int idx = blockIdx.x * 512 + threadIdx.x;
  if (idx >= BB * HWHW) return;
  const int b = idx / HWHW, p = idx - b * HWHW;
  const float* src = lidar + (size_t)b * CC * HWHW + p;
  unsigned short* dst = lidar_t + (size_t)idx * 128;
#pragma unroll
  for (int c8 = 0; c8 < 16; ++c8) {
    bf16x8 v;
#pragma unroll
    for (int e = 0; e < 8; ++e)
      v[e] = (short)f2bf(src[(size_t)(c8 * 8 + e) * HWHW]);
    ((bf16x8*)dst)[c8] = v;
  }
}

// ---------------------------------------------------------------------------
// k_scanA: bsum[b][blk] = sum of cnt_pix[b][blk*512 .. +512); also
// accumulates per-batch hit-pixel count into cntB[b].
// ---------------------------------------------------------------------------
__global__ __launch_bounds__(512) void k_scanA(
    const int* __restrict__ cnt, int* __restrict__ bsum,
    float* __restrict__ cntB)
{
  const int b = blockIdx.y, blk = blockIdx.x;
  const int idx = blk * 512 + threadIdx.x;
  int v = (idx < HWHW) ? cnt[(size_t)b * HWHW + idx] : 0;
  int h = (v > 0) ? 1 : 0;
  v = warpSumI(v);
  h = warpSumI(h);
  __shared__ int ws[8], hs[8];
  const int wave = threadIdx.x >> 6, lane = threadIdx.x & 63;
  if (lane == 0) { ws[wave] = v; hs[wave] = h; }
  __syncthreads();
  if (threadIdx.x == 0) {
    int sv = 0, sh = 0;
#pragma unroll
    for (int w = 0; w < 8; ++w) { sv += ws[w]; sh += hs[w]; }
    bsum[b * 64 + blk] = sv;
    atomicAdd(cntB + b, (float)sh);
  }
}

// ---------------------------------------------------------------------------
// k_scanB: boff[b][*] = exclusive scan of bsum[b][*] (64 entries, 1 wave)
// ---------------------------------------------------------------------------
__global__ __launch_bounds__(64) void k_scanB(
    const int* __restrict__ bsum, int* __restrict__ boff)
{
  const int b = blockIdx.x, t = threadIdx.x;
  const int v = bsum[b * 64 + t];
  int inc = v;
#pragma unroll
  for (int off = 1; off < 64; off <<= 1) {
    int u = __shfl_up(inc, off, 64);
    if (t >= off) inc += u;
  }
  boff[b * 64 + t] = inc - v;
}

// ---------------------------------------------------------------------------
// pipe_body: pipelined GEMM C[M,128cols@nblk] = A[M,KW] x W^T (MFMA 16x16x32).
// BM=128, BN=128, BK=32, 512 thr (8 waves 2x4, acc[4][2]).
// 3 LDS buffers, DIST=2 prefetch, counted vmcnt, raw s_barrier (round-13).
// AMODE 0: A f32 rows. AMODE 2: A bf16 rows gathered via pixw.
// AMODE 4: A = V-half of kv_bf in SORTED order x softmax*gate coef.
// EPI 0: bf16 rows. EPI 2: per-head logits vs kvb. EPI 3: linear bf16 +
// column sums -> meanr.
// ---------------------------------------------------------------------------
template<int KSTEPS, int KW, int AMODE, int EPI, int NOUT>
static __device__ void pipe_body(
    int mblk, int nblk, unsigned short* lds,
    const float* __restrict__ Af32, const unsigned short* __restrict__ Abf,
    const unsigned short* __restrict__ Bw, const float* __restrict__ bias,
    unsigned short* __restrict__ Dbf, const int* __restrict__ pixw,
    float* __restrict__ aux, const unsigned short* __restrict__ kvb,
    float* __restrict__ meanr, const float* __restrict__ smMp,
    const float* __restrict__ smSinvp, const float* __restrict__ gatep,
    const float* __restrict__ logp, const int* __restrict__ sortn)
{
  const int tid = threadIdx.x;
  const int lane = tid & 63, wave = tid >> 6;   // 8 waves
  const int wm = wave >> 2, wn = wave & 3;      // 2 x 4
  const int l16 = lane & 15, kg = lane >> 4;
  const int sr_rd = (l16 >> 1) & 3;             // read-side swizzle key

  // staging geometry: each thread owns one 16B chunk of one row
  const int row_s = wave * 16 + (lane >> 2);    // 0..127
  const int chunk_s = lane & 3;
  const int swz_s = chunk_s ^ ((lane >> 3) & 3);  // == chunk ^ ((row_s>>1)&3)
  const int a_dst = row_s * 32 + swz_s * 8;       // ushort idx (swizzled dest)

  const unsigned short* bsrc = Bw + (size_t)(nblk * 128 + row_s) * KW + swz_s * 8;

  const float* asrc_f32 = nullptr;
  const unsigned short* asrc_bf = nullptr;
  float coef4[4] = {0.f, 0.f, 0.f, 0.f};
  if constexpr (AMODE == 0) {
    asrc_f32 = Af32 + (size_t)(mblk * 128 + row_s) * KW + chunk_s * 8;
  } else if constexpr (AMODE == 2) {
    const int r = mblk * 128 + row_s;
    const int bb = r / NT;
    asrc_bf = Abf + ((size_t)bb * HWHW + pixw[r]) * 128 + swz_s * 8;
  } else {  // AMODE 4: sorted V
    const int r = mblk * 128 + row_s;
    const int bb = r / NT, pos = r - bb * NT;
    const int n = sortn[(size_t)bb * NT + pos];
    asrc_bf = Abf + ((size_t)bb * NT + n) * 256 + 128 + chunk_s * 8;
    const float ga = gatep[(size_t)bb * NT + n];
#pragma unroll
    for (int h = 0; h < 4; ++h) {
      const int bh = bb * NHEADS + h;
      coef4[h] = __expf(logp[(size_t)bh * NT + n] - smMp[bh]) * smSinvp[bh] * ga;
    }
  }

  f32x4 acc[4][2];
#pragma unroll
  for (int i = 0; i < 4; ++i)
#pragma unroll
    for (int j = 0; j < 2; ++j) acc[i][j] = (f32x4)0.0f;

  float4 afx[2], afy[2];   // AMODE 0
  bf16x8 av[2];            // AMODE 4

  auto issueA = [&](int kt, int s, int buf) {
    if constexpr (AMODE == 0) {
      afx[s] = *(const float4*)(asrc_f32 + kt * 32);
      afy[s] = *(const float4*)(asrc_f32 + kt * 32 + 4);
    } else if constexpr (AMODE == 2) {
      gll16(asrc_bf + kt * 32, &lds[buf * 8192 + wave * 512]);
    } else {
      av[s] = *(const bf16x8*)(asrc_bf + kt * 32);
    }
  };
  auto issueB = [&](int kt, int buf) {
    gll16(bsrc + kt * 32, &lds[buf * 8192 + 4096 + wave * 512]);
  };
  auto writeA = [&](int kt, int s, int buf) {
    bf16x8 v;
    if constexpr (AMODE == 0) {
      v[0] = (short)f2bf(afx[s].x); v[1] = (short)f2bf(afx[s].y);
      v[2] = (short)f2bf(afx[s].z); v[3] = (short)f2bf(afx[s].w);
      v[4] = (short)f2bf(afy[s].x); v[5] = (short)f2bf(afy[s].y);
      v[6] = (short)f2bf(afy[s].z); v[7] = (short)f2bf(afy[s].w);
    } else {
      const float c = coef4[kt];
#pragma unroll
      for (int e = 0; e < 8; ++e)
        v[e] = (short)f2bf(b2f((unsigned short)av[s][e]) * c);
    }
    *(bf16x8*)&lds[buf * 8192 + a_dst] = v;
  };
  auto compute = [&](int buf) {
    const int base = buf * 8192;
    bf16x8 a[4], b[2];
#pragma unroll
    for (int mf = 0; mf < 4; ++mf) {
      const int row = wm * 64 + mf * 16 + l16;
      a[mf] = *(const bf16x8*)&lds[base + row * 32 + ((kg ^ sr_rd) << 3)];
    }
#pragma unroll
    for (int nf = 0; nf < 2; ++nf) {
      const int row = wn * 32 + nf * 16 + l16;
      b[nf] = *(const bf16x8*)&lds[base + 4096 + row * 32 + ((kg ^ sr_rd) << 3)];
    }
#pragma unroll
    for (int mf = 0; mf < 4; ++mf)
#pragma unroll
      for (int nf = 0; nf < 2; ++nf)
        acc[mf][nf] =
            __builtin_amdgcn_mfma_f32_16x16x32_bf16(a[mf], b[nf], acc[mf][nf], 0, 0, 0);
  };

  // ---- prologue: 2 tiles in flight ----
  issueA(0, 0, 0); issueB(0, 0);
  issueA(1, 1, 1); issueB(1, 1);
  if constexpr (AMODE != 2) writeA(0, 0, 0);

  // ---- counted-vmcnt pipelined K-loop (T3+T4) ----
#pragma unroll
  for (int t = 0; t < KSTEPS; ++t) {
    if (t < KSTEPS - 1) {
      if constexpr (AMODE == 0) WAIT_VMCNT3(); else WAIT_VMCNT2();
    } else {
      WAIT_VMCNT0();
    }
    WAIT_LGKM0();                       // own writeA(t) committed
    __builtin_amdgcn_s_barrier();       // all waves: buf[t%3] valid
    __builtin_amdgcn_sched_barrier(0);
    if (t + 2 < KSTEPS) {               // prefetch into buf[(t-1)%3] (free now)
      issueA(t + 2, t & 1, (t + 2) % 3);
      issueB(t + 2, (t + 2) % 3);
    }
    compute(t % 3);
    if constexpr (AMODE != 2) {
      if (t + 1 < KSTEPS) writeA(t + 1, (t + 1) & 1, (t + 1) % 3);
    }
  }
  __syncthreads();

  float* scratch = (float*)lds;

  // ---- epilogue ----
  if constexpr (EPI == 0) {
#pragma unroll
    for (int mf = 0; mf < 4; ++mf) {
#pragma unroll
      for (int j = 0; j < 4; ++j) {
        const int row = mblk * 128 + wm * 64 + mf * 16 + kg * 4 + j;
        unsigned short* dr = Dbf + (size_t)row * NOUT + nblk * 128 + wn * 32 + l16;
#pragma unroll
        for (int nf = 0; nf < 2; ++nf)
          dr[nf * 16] = f2bf(acc[mf][nf][j]);
      }
    }
  } else if constexpr (EPI == 2) {
    // logits. Wave's 32-col span = head wn. Reduce over l16 group.
    float bv[2];
#pragma unroll
    for (int nf = 0; nf < 2; ++nf)
      bv[nf] = bias[wn * 32 + nf * 16 + l16];
#pragma unroll
    for (int mf = 0; mf < 4; ++mf) {
#pragma unroll
      for (int j = 0; j < 4; ++j) {
        const int rl = wm * 64 + mf * 16 + kg * 4 + j;
        const int row = mblk * 128 + rl;
        const unsigned short* kr = kvb + (size_t)row * 256 + wn * 32 + l16;
        float s = (acc[mf][0][j] + bv[0]) * b2f(kr[0]) +
                  (acc[mf][1][j] + bv[1]) * b2f(kr[16]);
        s += __shfl_xor(s, 8, 16); s += __shfl_xor(s, 4, 16);
        s += __shfl_xor(s, 2, 16); s += __shfl_xor(s, 1, 16);
        if (l16 == 0) scratch[rl * 4 + wn] = s;
      }
    }
    __syncthreads();
    if (tid < 128) {
      const int row = mblk * 128 + tid;
      const int bb = row / NT, n = row - bb * NT;
#pragma unroll
      for (int h = 0; h < 4; ++h)
        aux[((size_t)bb * NHEADS + h) * NT + n] = scratch[tid * 4 + h] * SCALE_C;
    }
  } else {
    // EPI 3: linear bf16 store + block column sums -> meanr
    if (tid < 256) scratch[tid] = 0.0f;
    __syncthreads();
    const int b0 = (mblk * 128) / NT;
#pragma unroll
    for (int mf = 0; mf < 4; ++mf) {
      const int baser = mblk * 128 + wm * 64 + mf * 16 + kg * 4;
      const int bb = baser / NT;          // uniform over j (NT % 4 == 0)
      const int bsel = (bb != b0) ? 1 : 0;
      float s[2] = {0.0f, 0.0f};
#pragma unroll
      for (int j = 0; j < 4; ++j) {
        const int row = baser + j;
        unsigned short* dr = Dbf + (size_t)row * 128 + wn * 32 + l16;
#pragma unroll
        for (int nf = 0; nf < 2; ++nf) {
          dr[nf * 16] = f2bf(acc[mf][nf][j]);
          s[nf] += acc[mf][nf][j];
        }
      }
#pragma unroll
      for (int nf = 0; nf < 2; ++nf)
        atomicAdd(&scratch[bsel * 128 + wn * 32 + nf * 16 + l16], s[nf]);
    }
    __syncthreads();
    const int b1 = (mblk * 128 + 127) / NT;
    if (tid < 128) atomicAdd(meanr + (size_t)b0 * 128 + tid, scratch[tid]);
    else if (tid < 256 && b1 != b0)
      atomicAdd(meanr + (size_t)b1 * 128 + (tid - 128), scratch[tid]);
  }
}

// ---------------------------------------------------------------------------
// k_kv: kv projection [80000,256] x [256,256]^T -> kv_bf. grid (625, 2).
// ---------------------------------------------------------------------------
__global__ __launch_bounds__(512) void k_kv(
    const float* __restrict__ tokens, const unsigned short* __restrict__ kvw,
    unsigned short* __restrict__ kv_bf)
{
  __shared__ unsigned short lds[24576];
  pipe_body<8, 256, 0, 0, 256>(blockIdx.x, blockIdx.y, lds, tokens, nullptr,
                               kvw, nullptr, kv_bf, nullptr, nullptr,
                               nullptr, nullptr, nullptr, nullptr,
                               nullptr, nullptr, nullptr);
}

// ---------------------------------------------------------------------------
// k_m2: blocks [0,256): scanC (start = boff + in-block exclusive scan);
//       blocks [256,881): q GEMM (gathered lidar_t rows) -> per-head logits.
// ---------------------------------------------------------------------------
__global__ __launch_bounds__(512) void k_m2(
    const int* __restrict__ cnt_pix, const int* __restrict__ boff,
    int* __restrict__ start, const unsigned short* __restrict__ lidar_t,
    const unsigned short* __restrict__ qwb, const float* __restrict__ qb,
    const int* __restrict__ pixw, float* __restrict__ logits,
    const unsigned short* __restrict__ kv_bf)
{
  __shared__ unsigned short lds[24576];
  const int bid = blockIdx.x;
  if (bid < 256) {
    __shared__ int ws[8];
    const int b = bid >> 6, blk = bid & 63;
    const int idx = blk * 512 + threadIdx.x;
    const int wave = threadIdx.x >> 6, lane = threadIdx.x & 63;
    int v = (idx < HWHW) ? cnt_pix[(size_t)b * HWHW + idx] : 0;
    int inc = v;
#pragma unroll
    for (int off = 1; off < 64; off <<= 1) {
      int u = __shfl_up(inc, off, 64);
      if (lane >= off) inc += u;
    }
    if (lane == 63) ws[wave] = inc;
    __syncthreads();
    int wo = 0;
#pragma unroll
    for (int w = 0; w < 8; ++w)
      if (w < wave) wo += ws[w];
    if (idx < HWHW)
      start[(size_t)b * HWHW + idx] = boff[b * 64 + blk] + wo + inc - v;
  } else {
    pipe_body<4, 128, 2, 2, 128>(bid - 256, 0, lds, nullptr, lidar_t, qwb,
                                 qb, nullptr, pixw, logits, kv_bf, nullptr,
                                 nullptr, nullptr, nullptr, nullptr, nullptr);
  }
}

// ---------------------------------------------------------------------------
// k_m3: blocks [0,128): smpart; blocks [128,441): reorder.
// ---------------------------------------------------------------------------
__global__ __launch_bounds__(256) void k_m3(
    const float* __restrict__ logits, float* __restrict__ pm,
    float* __restrict__ ps, const int* __restrict__ pix_ws,
    const int* __restrict__ start, int* __restrict__ fill,
    int* __restrict__ sortn)
{
  const int bid = blockIdx.x;
  if (bid < 128) {
    const int ch = bid & 7, bh = bid >> 3;
    const float* L = logits + (size_t)bh * NT + ch * 2500;
    const int tid = threadIdx.x;
    __shared__ float sred[4];

    float m = -INFINITY;
    for (int i = tid; i < 2500; i += 256) m = fmaxf(m, L[i]);
    m = warpMax(m);
    if ((tid & 63) == 0) sred[tid >> 6] = m;
    __syncthreads();
    m = fmaxf(fmaxf(sred[0], sred[1]), fmaxf(sred[2], sred[3]));

    float s = 0.0f;
    for (int i = tid; i < 2500; i += 256) s += __expf(L[i] - m);
    s = warpSum(s);
    __syncthreads();
    if ((tid & 63) == 0) sred[tid >> 6] = s;
    __syncthreads();
    if (tid == 0) {
      pm[bh * 8 + ch] = m;
      ps[bh * 8 + ch] = sred[0] + sred[1] + sred[2] + sred[3];
    }
  } else {
    const int t = (bid - 128) * 256 + threadIdx.x;
    if (t >= MTOT) return;
    const int b = t / NT, n = t - b * NT;
    const int pix = pix_ws[t];
    const int pos = atomicAdd(fill + (size_t)b * HWHW + pix, 1);
    sortn[(size_t)b * NT + start[(size_t)b * HWHW + pix] + pos] = n;
  }
}

// ---------------------------------------------------------------------------
// k_smfix: combine softmax partials -> smM, smSinv.
// ---------------------------------------------------------------------------
__global__ __launch_bounds__(64) void k_smfix(
    const float* __restrict__ pm, const float* __restrict__ ps,
    float* __restrict__ smM, float* __restrict__ smSinv)
{
  const int t = threadIdx.x;
  if (t >= BB * NHEADS) return;
  float M = -INFINITY;
#pragma unroll
  for (int c = 0; c < 8; ++c) M = fmaxf(M, pm[t * 8 + c]);
  float S = 0.0f;
#pragma unroll
  for (int c = 0; c < 8; ++c) S += ps[t * 8 + c] * __expf(pm[t * 8 + c] - M);
  smM[t] = M;
  smSinv[t] = 1.0f / S;
}

// ---------------------------------------------------------------------------
// k_out: out projection over SORTED tokens -> out_tok + column sums.
// ---------------------------------------------------------------------------
__global__ __launch_bounds__(512) void k_out(
    const unsigned short* __restrict__ kv_bf, const unsigned short* __restrict__ owb,
    unsigned short* __restrict__ out_tok, float* __restrict__ meanr,
    const float* __restrict__ smM, const float* __restrict__ smSinv,
    const float* __restrict__ gate, const float* __restrict__ logits,
    const int* __restrict__ sortn)
{
  __shared__ unsigned short lds[24576];
  pipe_body<4, 128, 4, 3, 128>(blockIdx.x, 0, lds, nullptr, kv_bf, owb,
                               nullptr, out_tok, nullptr, nullptr, nullptr,
                               meanr, smM, smSinv, gate, logits, sortn);
}

// ---------------------------------------------------------------------------
// k_final2: out[b][c][hw] = lidar + (delta - mean*mask)*alpha*gamma where
// delta[p][c] = sum over p's tokens of out_tok rows (sorted -> contiguous).
// ---------------------------------------------------------------------------
__global__ __launch_bounds__(512) void k_final2(
    const float* __restrict__ lidar, const float* __restrict__ alpha,
    const int* __restrict__ cnt_pix, const int* __restrict__ start,
    const unsigned short* __restrict__ out_tok,
    const float* __restrict__ mean_raw, const float* __restrict__ cntB,
    float* __restrict__ out)
{
  __shared__ float tile[80 * 136];
  const int b = blockIdx.y;
  const int p0 = blockIdx.x * 80;
  const int t = threadIdx.x;

  // phase 1: per-pixel token reduction (16 pixel-groups x 32 lanes)
  const int g = t >> 5, l32 = t & 31;
#pragma unroll
  for (int i = 0; i < 5; ++i) {
    const int pl = i * 16 + g;            // 0..79
    const int p = p0 + pl;
    const int st = start[(size_t)b * HWHW + p];
    const int cn = cnt_pix[(size_t)b * HWHW + p];
    float4 a = make_float4(0.0f, 0.0f, 0.0f, 0.0f);
    const unsigned short* rp = out_tok + ((size_t)b * NT + st) * 128 + l32 * 4;
    for (int k = 0; k < cn; ++k) {
      const ushort4 u = *(const ushort4*)(rp + (size_t)k * 128);
      a.x += b2f(u.x); a.y += b2f(u.y); a.z += b2f(u.z); a.w += b2f(u.w);
    }
    *(float4*)&tile[pl * 136 + ((l32 ^ (pl & 7)) << 2)] = a;
  }
  __syncthreads();

  // phase 2: transpose + final combine
  const int c = t >> 2, sub = t & 3;
  const int cq = c >> 2, cr = c & 3;
  const float mn = mean_raw[b * 128 + c] / (cntB[b] + EPS_C);
  const size_t cbase = ((size_t)b * CC + c) * HWHW + p0;
  const int* cnb = cnt_pix + (size_t)b * HWHW + p0;
#pragma unroll
  for (int j = 0; j < 5; ++j) {
    const int pq = j * 16 + sub * 4;
    float4 d;
    d.x = tile[(pq + 0) * 136 + (((cq ^ ((pq + 0) & 7)) << 2) | cr)];
    d.y = tile[(pq + 1) * 136 + (((cq ^ ((pq + 1) & 7)) << 2) | cr)];
    d.z = tile[(pq + 2) * 136 + (((cq ^ ((pq + 2) & 7)) << 2) | cr)];
    d.w = tile[(pq + 3) * 136 + (((cq ^ ((pq + 3) & 7)) << 2) | cr)];
    const float4 li = *(const float4*)(lidar + cbase + pq);
    const float4 al = *(const float4*)(alpha + p0 + pq);
    const int4 hc = *(const int4*)(cnb + pq);
    float4 o;
    o.x = li.x + (d.x - (hc.x > 0 ? mn : 0.0f)) * al.x * GAMMA_C;
    o.y = li.y + (d.y - (hc.y > 0 ? mn : 0.0f)) * al.y * GAMMA_C;
    o.z = li.z + (d.z - (hc.z > 0 ? mn : 0.0f)) * al.z * GAMMA_C;
    o.w = li.w + (d.w - (hc.w > 0 ? mn : 0.0f)) * al.w * GAMMA_C;
    *(float4*)(out + cbase + pq) = o;
  }
}

// ---------------------------------------------------------------------------
extern "C" void kernel_launch(void* const* d_in, const int* in_sizes, int n_in,
                              void* d_out, int out_size, void* d_ws, size_t ws_size,
                              hipStream_t stream)
{
  const float* lidar  = (const float*)d_in[0];
  const float* tokens = (const float*)d_in[1];
  const float* gate   = (const float*)d_in[2];
  const float* alpha  = (const float*)d_in[3];
  const float* q_w    = (const float*)d_in[4];
  const float* q_b    = (const float*)d_in[5];
  const float* k_w    = (const float*)d_in[6];
  const float* v_w    = (const float*)d_in[7];
  const float* out_w  = (const float*)d_in[8];
  const int*   cidx   = (const int*)d_in[9];
  float* out = (float*)d_out;

  char* W = (char*)d_ws;
  unsigned short* kv_bf   = (unsigned short*)(W + 0);          // 40,960,000
  unsigned short* lidar_t = (unsigned short*)(W + 40960000);   // 33,177,600
  unsigned short* out_tok = (unsigned short*)(W + 74137600);   // 20,480,000
  float* logits  = (float*)(W + 94617600);                     //  1,280,000
  int*   pix_ws  = (int*)(W + 95897600);                       //    320,000
  int*   sortn   = (int*)(W + 96217600);                       //    320,000
  int*   cnt_pix = (int*)(W + 96537600);                       //    518,400
  int*   start   = (int*)(W + 97056000);                       //    518,400
  int*   fill    = (int*)(W + 97574400);                       //    518,400
  float* mean_raw = (float*)(W + 98092800);                    //      2,048
  float* cntB     = (float*)(W + 98094848);                    //         64
  unsigned short* kvw_bf = (unsigned short*)(W + 98094912);    //    131,072
  unsigned short* qw_bf  = (unsigned short*)(W + 98225984);    //     32,768
  unsigned short* ow_bf  = (unsigned short*)(W + 98258752);    //     32,768
  float* pm     = (float*)(W + 98291520);                      //        512
  float* ps     = (float*)(W + 98292032);                      //        512
  float* smM    = (float*)(W + 98292544);                      //         64
  float* smSinv = (float*)(W + 98292608);                      //         64
  int*   bsum   = (int*)(W + 98292672);                        //      1,024
  int*   boff   = (int*)(W + 98293696);                        //      1,024

  hipMemsetAsync(cnt_pix, 0, (size_t)BB * HWHW * sizeof(int), stream);
  hipMemsetAsync(fill, 0, (size_t)BB * HWHW * sizeof(int), stream);
  hipMemsetAsync(mean_raw, 0, 2048 + 64, stream);

  k_prep_pix<<<dim3(409), 256, 0, stream>>>(k_w, v_w, q_w, out_w, kvw_bf,
                                            qw_bf, ow_bf, cidx, pix_ws, cnt_pix);
  k_tr2b<<<dim3(254), 512, 0, stream>>>(lidar, lidar_t);
  k_scanA<<<dim3(64, BB), 512, 0, stream>>>(cnt_pix, bsum, cntB);
  k_scanB<<<dim3(BB), 64, 0, stream>>>(bsum, boff);
  // kv projection: [80000,256] x [256,256]^T -> kv_bf
  k_kv<<<dim3(625, 2), 512, 0, stream>>>(tokens, kvw_bf, kv_bf);
  // M2: scanC + q GEMM/logits
  k_m2<<<dim3(881), 512, 0, stream>>>(cnt_pix, boff, start, lidar_t, qw_bf,
                                      q_b, pix_ws, logits, kv_bf);
  // M3: smpart + reorder
  k_m3<<<dim3(441), 256, 0, stream>>>(logits, pm, ps, pix_ws, start, fill, sortn);
  k_smfix<<<dim3(1), 64, 0, stream>>>(pm, ps, smM, smSinv);
  // out projection over SORTED tokens -> out_tok (linear bf16) + mean sums
  k_out<<<dim3(625), 512, 0, stream>>>(kv_bf, ow_bf, out_tok, mean_raw,
                                       smM, smSinv, gate, logits, sortn);
  k_final2<<<dim3(405, BB), 512, 0, stream>>>(lidar, alpha, cnt_pix, start,
                                              out_tok, mean_raw, cntB, out);
}

// Round 20
// 175.063 us; speedup vs baseline: 1.1581x; 1.0550x over previous
//
#include <hip/hip_runtime.h>

#define BB 4
#define CC 128
#define HH 180
#define WWW 180
#define HWHW (HH*WWW)       // 32400
#define CCAMD 256
#define NHEADS 4
#define HDD 128
#define NT 20000
#define MTOT 80000          // B*N, = 625 * 128 exactly
#define GAMMA_C 0.08f
#define EPS_C 1e-6f
#define SCALE_C 0.17677669529663687f  // 1/sqrt(32)

typedef short bf16x8 __attribute__((ext_vector_type(8)));
typedef float f32x4 __attribute__((ext_vector_type(4)));

typedef __attribute__((address_space(1))) const unsigned int GU;
typedef __attribute__((address_space(3))) unsigned int LU;

static __device__ __forceinline__ void gll16(const void* g, void* l) {
  __builtin_amdgcn_global_load_lds((GU*)g, (LU*)l, 16, 0, 0);
}

#define WAIT_VMCNT0() asm volatile("s_waitcnt vmcnt(0)" ::: "memory")
#define WAIT_VMCNT2() asm volatile("s_waitcnt vmcnt(2)" ::: "memory")
#define WAIT_VMCNT3() asm volatile("s_waitcnt vmcnt(3)" ::: "memory")
#define WAIT_LGKM0()  asm volatile("s_waitcnt lgkmcnt(0)" ::: "memory")

static __device__ __forceinline__ unsigned short f2bf(float x) {
  unsigned int b = __float_as_uint(x);
  unsigned int r = (b + 0x7fffu + ((b >> 16) & 1u)) >> 16;
  return (unsigned short)r;
}
static __device__ __forceinline__ float b2f(unsigned short u) {
  return __uint_as_float(((unsigned int)u) << 16);
}

static __device__ __forceinline__ float warpMax(float v) {
#pragma unroll
  for (int o = 32; o >= 1; o >>= 1) v = fmaxf(v, __shfl_xor(v, o));
  return v;
}
static __device__ __forceinline__ float warpSum(float v) {
#pragma unroll
  for (int o = 32; o >= 1; o >>= 1) v += __shfl_xor(v, o);
  return v;
}
static __device__ __forceinline__ int warpSumI(int v) {
#pragma unroll
  for (int o = 32; o >= 1; o >>= 1) v += __shfl_xor(v, o);
  return v;
}

// ---------------------------------------------------------------------------
// k_prep_pix: blocks 0..95: weight f32->bf16; blocks 96..408: pixel indices +
// int histogram cnt_pix[b][pix]++.
// ---------------------------------------------------------------------------
__global__ __launch_bounds__(256) void k_prep_pix(
    const float* __restrict__ kw, const float* __restrict__ vw,
    const float* __restrict__ qw, const float* __restrict__ ow,
    unsigned short* __restrict__ kvw, unsigned short* __restrict__ qwb,
    unsigned short* __restrict__ owb, const int* __restrict__ cidx,
    int* __restrict__ pix_ws, int* __restrict__ cnt_pix)
{
  if (blockIdx.x < 96) {
    const int t = blockIdx.x * 256 + threadIdx.x;  // one float4 per thread
    float4 f;
    unsigned short* dst;
    if (t < 16384) {           // kv: 65536 elems
      f = (t < 8192) ? ((const float4*)kw)[t] : ((const float4*)vw)[t - 8192];
      dst = kvw + (size_t)t * 4;
    } else if (t < 20480) {    // q: 16384 elems
      const int i = t - 16384;
      f = ((const float4*)qw)[i];
      dst = qwb + (size_t)i * 4;
    } else {                   // out: 16384 elems
      const int i = t - 20480;
      f = ((const float4*)ow)[i];
      dst = owb + (size_t)i * 4;
    }
    ushort4 u;
    u.x = f2bf(f.x); u.y = f2bf(f.y); u.z = f2bf(f.z); u.w = f2bf(f.w);
    *(ushort4*)dst = u;
  } else {
    const int t = (blockIdx.x - 96) * 256 + threadIdx.x;
    if (t >= MTOT) return;
    const int2 ij = *(const int2*)(cidx + (size_t)t * 2);
    int ii = ij.x; ii = ii < 0 ? 0 : (ii > HH - 1 ? HH - 1 : ii);
    int jj = ij.y; jj = jj < 0 ? 0 : (jj > WWW - 1 ? WWW - 1 : jj);
    const int pix = ii * WWW + jj;
    pix_ws[t] = pix;
    atomicAdd(cnt_pix + (size_t)(t / NT) * HWHW + pix, 1);
  }
}

// ---------------------------------------------------------------------------
// k_tr2c: lidar_t[b][p][:] = lidar[b][:][p] via LDS-staged transpose.
// 64-pixel tiles; phase 1 reads float4-coalesced along pixels into a
// quad-XOR-swizzled bf16 tile; phase 2 stores fully-coalesced 16B chunks.
// ---------------------------------------------------------------------------
__global__ __launch_bounds__(256) void k_tr2c(
    const float* __restrict__ lidar, unsigned short* __restrict__ lidar_t)
{
  __shared__ unsigned short tile[64 * 136];
  const int b = blockIdx.y;
  const int p0 = blockIdx.x * 64;
  const int t = threadIdx.x;

  // phase 1: (c, p4) items; float4 read along pixels; swizzled LDS write
#pragma unroll
  for (int i = 0; i < 8; ++i) {
    const int it = i * 256 + t;           // 2048 items
    const int c = it >> 4, p4 = it & 15;
    const int pg = p0 + p4 * 4;
    if (pg < HWHW) {
      const float4 f =
          *(const float4*)(lidar + ((size_t)b * CC + c) * HWHW + pg);
      const int cq = c >> 2, cr = c & 3;
      float fe[4] = {f.x, f.y, f.z, f.w};
#pragma unroll
      for (int e = 0; e < 4; ++e) {
        const int px = p4 * 4 + e;
        tile[px * 136 + (((cq ^ (px & 7)) << 2) | cr)] = f2bf(fe[e]);
      }
    }
  }
  __syncthreads();

  // phase 2: (px, ch) items; two ushort4 LDS reads; coalesced 16B store
#pragma unroll
  for (int i = 0; i < 4; ++i) {
    const int it = i * 256 + t;           // 1024 items
    const int px = it >> 4, ch = it & 15;
    const int pg = p0 + px;
    if (pg >= HWHW) continue;
    const int k = px & 7;
    const ushort4 u0 = *(const ushort4*)&tile[px * 136 + (((ch * 2) ^ k) << 2)];
    const ushort4 u1 = *(const ushort4*)&tile[px * 136 + (((ch * 2 + 1) ^ k) << 2)];
    bf16x8 v;
    v[0] = (short)u0.x; v[1] = (short)u0.y; v[2] = (short)u0.z; v[3] = (short)u0.w;
    v[4] = (short)u1.x; v[5] = (short)u1.y; v[6] = (short)u1.z; v[7] = (short)u1.w;
    *(bf16x8*)(lidar_t + ((size_t)b * HWHW + pg) * 128 + ch * 8) = v;
  }
}

// ---------------------------------------------------------------------------
// k_scanA: bsum[b][blk] = sum of cnt_pix[b][blk*512 .. +512); also
// accumulates per-batch hit-pixel count into cntB[b].
// ---------------------------------------------------------------------------
__global__ __launch_bounds__(512) void k_scanA(
    const int* __restrict__ cnt, int* __restrict__ bsum,
    float* __restrict__ cntB)
{
  const int b = blockIdx.y, blk = blockIdx.x;
  const int idx = blk * 512 + threadIdx.x;
  int v = (idx < HWHW) ? cnt[(size_t)b * HWHW + idx] : 0;
  int h = (v > 0) ? 1 : 0;
  v = warpSumI(v);
  h = warpSumI(h);
  __shared__ int ws[8], hs[8];
  const int wave = threadIdx.x >> 6, lane = threadIdx.x & 63;
  if (lane == 0) { ws[wave] = v; hs[wave] = h; }
  __syncthreads();
  if (threadIdx.x == 0) {
    int sv = 0, sh = 0;
#pragma unroll
    for (int w = 0; w < 8; ++w) { sv += ws[w]; sh += hs[w]; }
    bsum[b * 64 + blk] = sv;
    atomicAdd(cntB + b, (float)sh);
  }
}

// ---------------------------------------------------------------------------
// k_scanB: boff[b][*] = exclusive scan of bsum[b][*] (64 entries, 1 wave)
// ---------------------------------------------------------------------------
__global__ __launch_bounds__(64) void k_scanB(
    const int* __restrict__ bsum, int* __restrict__ boff)
{
  const int b = blockIdx.x, t = threadIdx.x;
  const int v = bsum[b * 64 + t];
  int inc = v;
#pragma unroll
  for (int off = 1; off < 64; off <<= 1) {
    int u = __shfl_up(inc, off, 64);
    if (t >= off) inc += u;
  }
  boff[b * 64 + t] = inc - v;
}

// ---------------------------------------------------------------------------
// pipe_body: pipelined GEMM C[M,128cols@nblk] = A[M,KW] x W^T (MFMA 16x16x32).
// BM=128, BN=128, BK=32, 512 thr (8 waves 2x4, acc[4][2]).
// 3 LDS buffers, DIST=2 prefetch, counted vmcnt, raw s_barrier (round-13).
// AMODE 0: A f32 rows. AMODE 2: A bf16 rows gathered via pixw.
// AMODE 4: A = V-half of kv_bf in SORTED order x softmax*gate coef.
// EPI 0: bf16 rows. EPI 2: per-head logits vs kvb. EPI 3: linear bf16 +
// column sums -> meanr.
// ---------------------------------------------------------------------------
template<int KSTEPS, int KW, int AMODE, int EPI, int NOUT>
static __device__ void pipe_body(
    int mblk, int nblk, unsigned short* lds,
    const float* __restrict__ Af32, const unsigned short* __restrict__ Abf,
    const unsigned short* __restrict__ Bw, const float* __restrict__ bias,
    unsigned short* __restrict__ Dbf, const int* __restrict__ pixw,
    float* __restrict__ aux, const unsigned short* __restrict__ kvb,
    float* __restrict__ meanr, const float* __restrict__ smMp,
    const float* __restrict__ smSinvp, const float* __restrict__ gatep,
    const float* __restrict__ logp, const int* __restrict__ sortn)
{
  const int tid = threadIdx.x;
  const int lane = tid & 63, wave = tid >> 6;   // 8 waves
  const int wm = wave >> 2, wn = wave & 3;      // 2 x 4
  const int l16 = lane & 15, kg = lane >> 4;
  const int sr_rd = (l16 >> 1) & 3;             // read-side swizzle key

  // staging geometry: each thread owns one 16B chunk of one row
  const int row_s = wave * 16 + (lane >> 2);    // 0..127
  const int chunk_s = lane & 3;
  const int swz_s = chunk_s ^ ((lane >> 3) & 3);  // == chunk ^ ((row_s>>1)&3)
  const int a_dst = row_s * 32 + swz_s * 8;       // ushort idx (swizzled dest)

  const unsigned short* bsrc = Bw + (size_t)(nblk * 128 + row_s) * KW + swz_s * 8;

  const float* asrc_f32 = nullptr;
  const unsigned short* asrc_bf = nullptr;
  float coef4[4] = {0.f, 0.f, 0.f, 0.f};
  if constexpr (AMODE == 0) {
    asrc_f32 = Af32 + (size_t)(mblk * 128 + row_s) * KW + chunk_s * 8;
  } else if constexpr (AMODE == 2) {
    const int r = mblk * 128 + row_s;
    const int bb = r / NT;
    asrc_bf = Abf + ((size_t)bb * HWHW + pixw[r]) * 128 + swz_s * 8;
  } else {  // AMODE 4: sorted V
    const int r = mblk * 128 + row_s;
    const int bb = r / NT, pos = r - bb * NT;
    const int n = sortn[(size_t)bb * NT + pos];
    asrc_bf = Abf + ((size_t)bb * NT + n) * 256 + 128 + chunk_s * 8;
    const float ga = gatep[(size_t)bb * NT + n];
#pragma unroll
    for (int h = 0; h < 4; ++h) {
      const int bh = bb * NHEADS + h;
      coef4[h] = __expf(logp[(size_t)bh * NT + n] - smMp[bh]) * smSinvp[bh] * ga;
    }
  }

  f32x4 acc[4][2];
#pragma unroll
  for (int i = 0; i < 4; ++i)
#pragma unroll
    for (int j = 0; j < 2; ++j) acc[i][j] = (f32x4)0.0f;

  float4 afx[2], afy[2];   // AMODE 0
  bf16x8 av[2];            // AMODE 4

  auto issueA = [&](int kt, int s, int buf) {
    if constexpr (AMODE == 0) {
      afx[s] = *(const float4*)(asrc_f32 + kt * 32);
      afy[s] = *(const float4*)(asrc_f32 + kt * 32 + 4);
    } else if constexpr (AMODE == 2) {
      gll16(asrc_bf + kt * 32, &lds[buf * 8192 + wave * 512]);
    } else {
      av[s] = *(const bf16x8*)(asrc_bf + kt * 32);
    }
  };
  auto issueB = [&](int kt, int buf) {
    gll16(bsrc + kt * 32, &lds[buf * 8192 + 4096 + wave * 512]);
  };
  auto writeA = [&](int kt, int s, int buf) {
    bf16x8 v;
    if constexpr (AMODE == 0) {
      v[0] = (short)f2bf(afx[s].x); v[1] = (short)f2bf(afx[s].y);
      v[2] = (short)f2bf(afx[s].z); v[3] = (short)f2bf(afx[s].w);
      v[4] = (short)f2bf(afy[s].x); v[5] = (short)f2bf(afy[s].y);
      v[6] = (short)f2bf(afy[s].z); v[7] = (short)f2bf(afy[s].w);
    } else {
      const float c = coef4[kt];
#pragma unroll
      for (int e = 0; e < 8; ++e)
        v[e] = (short)f2bf(b2f((unsigned short)av[s][e]) * c);
    }
    *(bf16x8*)&lds[buf * 8192 + a_dst] = v;
  };
  auto compute = [&](int buf) {
    const int base = buf * 8192;
    bf16x8 a[4], b[2];
#pragma unroll
    for (int mf = 0; mf < 4; ++mf) {
      const int row = wm * 64 + mf * 16 + l16;
      a[mf] = *(const bf16x8*)&lds[base + row * 32 + ((kg ^ sr_rd) << 3)];
    }
#pragma unroll
    for (int nf = 0; nf < 2; ++nf) {
      const int row = wn * 32 + nf * 16 + l16;
      b[nf] = *(const bf16x8*)&lds[base + 4096 + row * 32 + ((kg ^ sr_rd) << 3)];
    }
#pragma unroll
    for (int mf = 0; mf < 4; ++mf)
#pragma unroll
      for (int nf = 0; nf < 2; ++nf)
        acc[mf][nf] =
            __builtin_amdgcn_mfma_f32_16x16x32_bf16(a[mf], b[nf], acc[mf][nf], 0, 0, 0);
  };

  // ---- prologue: 2 tiles in flight ----
  issueA(0, 0, 0); issueB(0, 0);
  issueA(1, 1, 1); issueB(1, 1);
  if constexpr (AMODE != 2) writeA(0, 0, 0);

  // ---- counted-vmcnt pipelined K-loop (T3+T4) ----
#pragma unroll
  for (int t = 0; t < KSTEPS; ++t) {
    if (t < KSTEPS - 1) {
      if constexpr (AMODE == 0) WAIT_VMCNT3(); else WAIT_VMCNT2();
    } else {
      WAIT_VMCNT0();
    }
    WAIT_LGKM0();                       // own writeA(t) committed
    __builtin_amdgcn_s_barrier();       // all waves: buf[t%3] valid
    __builtin_amdgcn_sched_barrier(0);
    if (t + 2 < KSTEPS) {               // prefetch into buf[(t-1)%3] (free now)
      issueA(t + 2, t & 1, (t + 2) % 3);
      issueB(t + 2, (t + 2) % 3);
    }
    compute(t % 3);
    if constexpr (AMODE != 2) {
      if (t + 1 < KSTEPS) writeA(t + 1, (t + 1) & 1, (t + 1) % 3);
    }
  }
  __syncthreads();

  float* scratch = (float*)lds;

  // ---- epilogue ----
  if constexpr (EPI == 0) {
#pragma unroll
    for (int mf = 0; mf < 4; ++mf) {
#pragma unroll
      for (int j = 0; j < 4; ++j) {
        const int row = mblk * 128 + wm * 64 + mf * 16 + kg * 4 + j;
        unsigned short* dr = Dbf + (size_t)row * NOUT + nblk * 128 + wn * 32 + l16;
#pragma unroll
        for (int nf = 0; nf < 2; ++nf)
          dr[nf * 16] = f2bf(acc[mf][nf][j]);
      }
    }
  } else if constexpr (EPI == 2) {
    // logits. Wave's 32-col span = head wn. Reduce over l16 group.
    float bv[2];
#pragma unroll
    for (int nf = 0; nf < 2; ++nf)
      bv[nf] = bias[wn * 32 + nf * 16 + l16];
#pragma unroll
    for (int mf = 0; mf < 4; ++mf) {
#pragma unroll
      for (int j = 0; j < 4; ++j) {
        const int rl = wm * 64 + mf * 16 + kg * 4 + j;
        const int row = mblk * 128 + rl;
        const unsigned short* kr = kvb + (size_t)row * 256 + wn * 32 + l16;
        float s = (acc[mf][0][j] + bv[0]) * b2f(kr[0]) +
                  (acc[mf][1][j] + bv[1]) * b2f(kr[16]);
        s += __shfl_xor(s, 8, 16); s += __shfl_xor(s, 4, 16);
        s += __shfl_xor(s, 2, 16); s += __shfl_xor(s, 1, 16);
        if (l16 == 0) scratch[rl * 4 + wn] = s;
      }
    }
    __syncthreads();
    if (tid < 128) {
      const int row = mblk * 128 + tid;
      const int bb = row / NT, n = row - bb * NT;
#pragma unroll
      for (int h = 0; h < 4; ++h)
        aux[((size_t)bb * NHEADS + h) * NT + n] = scratch[tid * 4 + h] * SCALE_C;
    }
  } else {
    // EPI 3: linear bf16 store + block column sums -> meanr
    if (tid < 256) scratch[tid] = 0.0f;
    __syncthreads();
    const int b0 = (mblk * 128) / NT;
#pragma unroll
    for (int mf = 0; mf < 4; ++mf) {
      const int baser = mblk * 128 + wm * 64 + mf * 16 + kg * 4;
      const int bb = baser / NT;          // uniform over j (NT % 4 == 0)
      const int bsel = (bb != b0) ? 1 : 0;
      float s[2] = {0.0f, 0.0f};
#pragma unroll
      for (int j = 0; j < 4; ++j) {
        const int row = baser + j;
        unsigned short* dr = Dbf + (size_t)row * 128 + wn * 32 + l16;
#pragma unroll
        for (int nf = 0; nf < 2; ++nf) {
          dr[nf * 16] = f2bf(acc[mf][nf][j]);
          s[nf] += acc[mf][nf][j];
        }
      }
#pragma unroll
      for (int nf = 0; nf < 2; ++nf)
        atomicAdd(&scratch[bsel * 128 + wn * 32 + nf * 16 + l16], s[nf]);
    }
    __syncthreads();
    const int b1 = (mblk * 128 + 127) / NT;
    if (tid < 128) atomicAdd(meanr + (size_t)b0 * 128 + tid, scratch[tid]);
    else if (tid < 256 && b1 != b0)
      atomicAdd(meanr + (size_t)b1 * 128 + (tid - 128), scratch[tid]);
  }
}

// ---------------------------------------------------------------------------
// k_kv: kv projection [80000,256] x [256,256]^T -> kv_bf. grid (625, 2).
// ---------------------------------------------------------------------------
__global__ __launch_bounds__(512) void k_kv(
    const float* __restrict__ tokens, const unsigned short* __restrict__ kvw,
    unsigned short* __restrict__ kv_bf)
{
  __shared__ unsigned short lds[24576];
  pipe_body<8, 256, 0, 0, 256>(blockIdx.x, blockIdx.y, lds, tokens, nullptr,
                               kvw, nullptr, kv_bf, nullptr, nullptr,
                               nullptr, nullptr, nullptr, nullptr,
                               nullptr, nullptr, nullptr);
}

// ---------------------------------------------------------------------------
// k_m2: blocks [0,256): scanC (start = boff + in-block exclusive scan);
//       blocks [256,881): q GEMM (gathered lidar_t rows) -> per-head logits.
// ---------------------------------------------------------------------------
__global__ __launch_bounds__(512) void k_m2(
    const int* __restrict__ cnt_pix, const int* __restrict__ boff,
    int* __restrict__ start, const unsigned short* __restrict__ lidar_t,
    const unsigned short* __restrict__ qwb, const float* __restrict__ qb,
    const int* __restrict__ pixw, float* __restrict__ logits,
    const unsigned short* __restrict__ kv_bf)
{
  __shared__ unsigned short lds[24576];
  const int bid = blockIdx.x;
  if (bid < 256) {
    __shared__ int ws[8];
    const int b = bid >> 6, blk = bid & 63;
    const int idx = blk * 512 + threadIdx.x;
    const int wave = threadIdx.x >> 6, lane = threadIdx.x & 63;
    int v = (idx < HWHW) ? cnt_pix[(size_t)b * HWHW + idx] : 0;
    int inc = v;
#pragma unroll
    for (int off = 1; off < 64; off <<= 1) {
      int u = __shfl_up(inc, off, 64);
      if (lane >= off) inc += u;
    }
    if (lane == 63) ws[wave] = inc;
    __syncthreads();
    int wo = 0;
#pragma unroll
    for (int w = 0; w < 8; ++w)
      if (w < wave) wo += ws[w];
    if (idx < HWHW)
      start[(size_t)b * HWHW + idx] = boff[b * 64 + blk] + wo + inc - v;
  } else {
    pipe_body<4, 128, 2, 2, 128>(bid - 256, 0, lds, nullptr, lidar_t, qwb,
                                 qb, nullptr, pixw, logits, kv_bf, nullptr,
                                 nullptr, nullptr, nullptr, nullptr, nullptr);
  }
}

// ---------------------------------------------------------------------------
// k_m3: blocks [0,128): smpart; blocks [128,441): reorder.
// ---------------------------------------------------------------------------
__global__ __launch_bounds__(256) void k_m3(
    const float* __restrict__ logits, float* __restrict__ pm,
    float* __restrict__ ps, const int* __restrict__ pix_ws,
    const int* __restrict__ start, int* __restrict__ fill,
    int* __restrict__ sortn)
{
  const int bid = blockIdx.x;
  if (bid < 128) {
    const int ch = bid & 7, bh = bid >> 3;
    const float* L = logits + (size_t)bh * NT + ch * 2500;
    const int tid = threadIdx.x;
    __shared__ float sred[4];

    float m = -INFINITY;
    for (int i = tid; i < 2500; i += 256) m = fmaxf(m, L[i]);
    m = warpMax(m);
    if ((tid & 63) == 0) sred[tid >> 6] = m;
    __syncthreads();
    m = fmaxf(fmaxf(sred[0], sred[1]), fmaxf(sred[2], sred[3]));

    float s = 0.0f;
    for (int i = tid; i < 2500; i += 256) s += __expf(L[i] - m);
    s = warpSum(s);
    __syncthreads();
    if ((tid & 63) == 0) sred[tid >> 6] = s;
    __syncthreads();
    if (tid == 0) {
      pm[bh * 8 + ch] = m;
      ps[bh * 8 + ch] = sred[0] + sred[1] + sred[2] + sred[3];
    }
  } else {
    const int t = (bid - 128) * 256 + threadIdx.x;
    if (t >= MTOT) return;
    const int b = t / NT, n = t - b * NT;
    const int pix = pix_ws[t];
    const int pos = atomicAdd(fill + (size_t)b * HWHW + pix, 1);
    sortn[(size_t)b * NT + start[(size_t)b * HWHW + pix] + pos] = n;
  }
}

// ---------------------------------------------------------------------------
// k_smfix: combine softmax partials -> smM, smSinv.
// ---------------------------------------------------------------------------
__global__ __launch_bounds__(64) void k_smfix(
    const float* __restrict__ pm, const float* __restrict__ ps,
    float* __restrict__ smM, float* __restrict__ smSinv)
{
  const int t = threadIdx.x;
  if (t >= BB * NHEADS) return;
  float M = -INFINITY;
#pragma unroll
  for (int c = 0; c < 8; ++c) M = fmaxf(M, pm[t * 8 + c]);
  float S = 0.0f;
#pragma unroll
  for (int c = 0; c < 8; ++c) S += ps[t * 8 + c] * __expf(pm[t * 8 + c] - M);
  smM[t] = M;
  smSinv[t] = 1.0f / S;
}

// ---------------------------------------------------------------------------
// k_out: out projection over SORTED tokens -> out_tok + column sums.
// ---------------------------------------------------------------------------
__global__ __launch_bounds__(512) void k_out(
    const unsigned short* __restrict__ kv_bf, const unsigned short* __restrict__ owb,
    unsigned short* __restrict__ out_tok, float* __restrict__ meanr,
    const float* __restrict__ smM, const float* __restrict__ smSinv,
    const float* __restrict__ gate, const float* __restrict__ logits,
    const int* __restrict__ sortn)
{
  __shared__ unsigned short lds[24576];
  pipe_body<4, 128, 4, 3, 128>(blockIdx.x, 0, lds, nullptr, kv_bf, owb,
                               nullptr, out_tok, nullptr, nullptr, nullptr,
                               meanr, smM, smSinv, gate, logits, sortn);
}

// ---------------------------------------------------------------------------
// k_final2: out[b][c][hw] = lidar + (delta - mean*mask)*alpha*gamma where
// delta[p][c] = sum over p's tokens of out_tok rows (sorted -> contiguous).
// ---------------------------------------------------------------------------
__global__ __launch_bounds__(512) void k_final2(
    const float* __restrict__ lidar, const float* __restrict__ alpha,
    const int* __restrict__ cnt_pix, const int* __restrict__ start,
    const unsigned short* __restrict__ out_tok,
    const float* __restrict__ mean_raw, const float* __restrict__ cntB,
    float* __restrict__ out)
{
  __shared__ float tile[80 * 136];
  const int b = blockIdx.y;
  const int p0 = blockIdx.x * 80;
  const int t = threadIdx.x;

  // phase 1: per-pixel token reduction (16 pixel-groups x 32 lanes)
  const int g = t >> 5, l32 = t & 31;
#pragma unroll
  for (int i = 0; i < 5; ++i) {
    const int pl = i * 16 + g;            // 0..79
    const int p = p0 + pl;
    const int st = start[(size_t)b * HWHW + p];
    const int cn = cnt_pix[(size_t)b * HWHW + p];
    float4 a = make_float4(0.0f, 0.0f, 0.0f, 0.0f);
    const unsigned short* rp = out_tok + ((size_t)b * NT + st) * 128 + l32 * 4;
    for (int k = 0; k < cn; ++k) {
      const ushort4 u = *(const ushort4*)(rp + (size_t)k * 128);
      a.x += b2f(u.x); a.y += b2f(u.y); a.z += b2f(u.z); a.w += b2f(u.w);
    }
    *(float4*)&tile[pl * 136 + ((l32 ^ (pl & 7)) << 2)] = a;
  }
  __syncthreads();

  // phase 2: transpose + final combine
  const int c = t >> 2, sub = t & 3;
  const int cq = c >> 2, cr = c & 3;
  const float mn = mean_raw[b * 128 + c] / (cntB[b] + EPS_C);
  const size_t cbase = ((size_t)b * CC + c) * HWHW + p0;
  const int* cnb = cnt_pix + (size_t)b * HWHW + p0;
#pragma unroll
  for (int j = 0; j < 5; ++j) {
    const int pq = j * 16 + sub * 4;
    float4 d;
    d.x = tile[(pq + 0) * 136 + (((cq ^ ((pq + 0) & 7)) << 2) | cr)];
    d.y = tile[(pq + 1) * 136 + (((cq ^ ((pq + 1) & 7)) << 2) | cr)];
    d.z = tile[(pq + 2) * 136 + (((cq ^ ((pq + 2) & 7)) << 2) | cr)];
    d.w = tile[(pq + 3) * 136 + (((cq ^ ((pq + 3) & 7)) << 2) | cr)];
    const float4 li = *(const float4*)(lidar + cbase + pq);
    const float4 al = *(const float4*)(alpha + p0 + pq);
    const int4 hc = *(const int4*)(cnb + pq);
    float4 o;
    o.x = li.x + (d.x - (hc.x > 0 ? mn : 0.0f)) * al.x * GAMMA_C;
    o.y = li.y + (d.y - (hc.y > 0 ? mn : 0.0f)) * al.y * GAMMA_C;
    o.z = li.z + (d.z - (hc.z > 0 ? mn : 0.0f)) * al.z * GAMMA_C;
    o.w = li.w + (d.w - (hc.w > 0 ? mn : 0.0f)) * al.w * GAMMA_C;
    *(float4*)(out + cbase + pq) = o;
  }
}

// ---------------------------------------------------------------------------
extern "C" void kernel_launch(void* const* d_in, const int* in_sizes, int n_in,
                              void* d_out, int out_size, void* d_ws, size_t ws_size,
                              hipStream_t stream)
{
  const float* lidar  = (const float*)d_in[0];
  const float* tokens = (const float*)d_in[1];
  const float* gate   = (const float*)d_in[2];
  const float* alpha  = (const float*)d_in[3];
  const float* q_w    = (const float*)d_in[4];
  const float* q_b    = (const float*)d_in[5];
  const float* k_w    = (const float*)d_in[6];
  const float* v_w    = (const float*)d_in[7];
  const float* out_w  = (const float*)d_in[8];
  const int*   cidx   = (const int*)d_in[9];
  float* out = (float*)d_out;

  char* W = (char*)d_ws;
  unsigned short* kv_bf   = (unsigned short*)(W + 0);          // 40,960,000
  unsigned short* lidar_t = (unsigned short*)(W + 40960000);   // 33,177,600
  unsigned short* out_tok = (unsigned short*)(W + 74137600);   // 20,480,000
  float* logits  = (float*)(W + 94617600);                     //  1,280,000
  int*   pix_ws  = (int*)(W + 95897600);                       //    320,000
  int*   sortn   = (int*)(W + 96217600);                       //    320,000
  int*   cnt_pix = (int*)(W + 96537600);                       //    518,400
  int*   start   = (int*)(W + 97056000);                       //    518,400
  int*   fill    = (int*)(W + 97574400);                       //    518,400
  float* mean_raw = (float*)(W + 98092800);                    //      2,048
  float* cntB     = (float*)(W + 98094848);                    //         64
  unsigned short* kvw_bf = (unsigned short*)(W + 98094912);    //    131,072
  unsigned short* qw_bf  = (unsigned short*)(W + 98225984);    //     32,768
  unsigned short* ow_bf  = (unsigned short*)(W + 98258752);    //     32,768
  float* pm     = (float*)(W + 98291520);                      //        512
  float* ps     = (float*)(W + 98292032);                      //        512
  float* smM    = (float*)(W + 98292544);                      //         64
  float* smSinv = (float*)(W + 98292608);                      //         64
  int*   bsum   = (int*)(W + 98292672);                        //      1,024
  int*   boff   = (int*)(W + 98293696);                        //      1,024

  hipMemsetAsync(cnt_pix, 0, (size_t)BB * HWHW * sizeof(int), stream);
  hipMemsetAsync(fill, 0, (size_t)BB * HWHW * sizeof(int), stream);
  hipMemsetAsync(mean_raw, 0, 2048 + 64, stream);

  k_prep_pix<<<dim3(409), 256, 0, stream>>>(k_w, v_w, q_w, out_w, kvw_bf,
                                            qw_bf, ow_bf, cidx, pix_ws, cnt_pix);
  k_tr2c<<<dim3(507, BB), 256, 0, stream>>>(lidar, lidar_t);
  k_scanA<<<dim3(64, BB), 512, 0, stream>>>(cnt_pix, bsum, cntB);
  k_scanB<<<dim3(BB), 64, 0, stream>>>(bsum, boff);
  // kv projection: [80000,256] x [256,256]^T -> kv_bf
  k_kv<<<dim3(625, 2), 512, 0, stream>>>(tokens, kvw_bf, kv_bf);
  // M2: scanC + q GEMM/logits
  k_m2<<<dim3(881), 512, 0, stream>>>(cnt_pix, boff, start, lidar_t, qw_bf,
                                      q_b, pix_ws, logits, kv_bf);
  // M3: smpart + reorder
  k_m3<<<dim3(441), 256, 0, stream>>>(logits, pm, ps, pix_ws, start, fill, sortn);
  k_smfix<<<dim3(1), 64, 0, stream>>>(pm, ps, smM, smSinv);
  // out projection over SORTED tokens -> out_tok (linear bf16) + mean sums
  k_out<<<dim3(625), 512, 0, stream>>>(kv_bf, ow_bf, out_tok, mean_raw,
                                       smM, smSinv, gate, logits, sortn);
  k_final2<<<dim3(405, BB), 512, 0, stream>>>(lidar, alpha, cnt_pix, start,
                                              out_tok, mean_raw, cntB, out);
}